// Round 14
// baseline (68.381 us; speedup 1.0000x reference)
//
#include <hip/hip_runtime.h>
#include <math.h>

#define NUM_MOE 64
#define DIM 64
#define CH 16            // float4 chunks per x row

typedef float f32x2 __attribute__((ext_vector_type(2)));
typedef float f32x4 __attribute__((ext_vector_type(4)));
typedef float f32x8 __attribute__((ext_vector_type(8)));

// Single-wave blocks, lane = token, ZERO LDS / barriers / merge phases.
// R10-R13 wave-lifetime algebra: waves lived ~8us but issued ~1.5us -- the
// cooperative-block staging/barrier/merge chain WAS the stall. This design
// deletes it. Register budget: R4 measured plain __launch_bounds__(64)
// grants 128 VGPRs (R5's 64-clamp came from the min-waves arg; R3's remat
// from 256-thread blocks). Live set here ~90: xv 64 + acc 4 + fold/addr.
// Grid 4096 one-wave blocks = exactly one residency generation
// (256 CU x 16 wave-slots at 4 waves/SIMD): no churn at all.
__global__ __launch_bounds__(64)
void moe_router_kernel(const float* __restrict__ x,
                       const float* __restrict__ W,
                       float* __restrict__ out,
                       int ntok) {
    const int lane = threadIdx.x;                    // 0..63
    const int t    = blockIdx.x * 64 + lane;         // one token per lane
    if (t >= ntok) return;

    // ---- x row -> 16 float4 registers (64 VGPR), loaded once ----
    const f32x4* __restrict__ xr4 = reinterpret_cast<const f32x4*>(x) + (size_t)t * CH;
    f32x4 xv[CH];
    #pragma unroll
    for (int k = 0; k < CH; ++k) xv[k] = xr4[k];

    const f32x8* __restrict__ W8 = reinterpret_cast<const f32x8*>(W);

    float m1 = -INFINITY, m2 = -INFINITY, Z = 0.0f;
    int   i1 = 0, i2 = 0;

    // 4 rolled groups (keeps body ~4KB, in icache); experts folded one at
    // a time -> minimal live state, no acc array to spill.
    #pragma unroll 1
    for (int g = 0; g < 4; ++g) {
        #pragma unroll
        for (int e = 0; e < 16; ++e) {
            const int ge = g * 16 + e;
            // two accumulator chains for dep-latency slack
            f32x2 a0 = {0.0f, 0.0f}, a1 = {0.0f, 0.0f};
            #pragma unroll
            for (int k8 = 0; k8 < 8; ++k8) {
                // uniform base + compile-time offset -> s_load_dwordx8
                const f32x8 w8 = W8[ge * 8 + k8];
                const f32x4 x0 = xv[2 * k8], x1 = xv[2 * k8 + 1];
                const f32x2 xa = {x0.x, x0.y}, xb = {x0.z, x0.w};
                const f32x2 xc = {x1.x, x1.y}, xd = {x1.z, x1.w};
                a0 = __builtin_elementwise_fma(xa, (f32x2){w8[0], w8[1]}, a0);
                a1 = __builtin_elementwise_fma(xb, (f32x2){w8[2], w8[3]}, a1);
                a0 = __builtin_elementwise_fma(xc, (f32x2){w8[4], w8[5]}, a0);
                a1 = __builtin_elementwise_fma(xd, (f32x2){w8[6], w8[7]}, a1);
            }
            const float v = (a0.x + a1.x) + (a0.y + a1.y);
            // fold into running Z + exact top-2 (strict '>' + ascending
            // order => lowest index wins ties, matching lax.top_k)
            Z += __expf(v);                          // logits ~N(0,1): no max-sub
            const bool b1 = v > m1;
            const bool b2 = v > m2;
            i2 = b1 ? i1 : (b2 ? ge : i2);
            m2 = b1 ? m1 : (b2 ? v : m2);
            i1 = b1 ? ge : i1;
            m1 = b1 ? v  : m1;
        }
    }

    // out[i1] = sigmoid((exp(m1)-exp(m2))/Z), out[i2] = 1 - out[i1]
    const float E1  = __expf(m1), E2 = __expf(m2);
    const float d12 = (E1 - E2) / Z;
    const float w1  = 1.0f / (1.0f + __expf(-d12));
    const float w2  = 1.0f - w1;

    // Build the sparse row in registers (compile-time j vs runtime i1/i2
    // -> v_cmp + cndmask) and store: lane fully owns its 4x 64B lines,
    // 4 temporally-adjacent dwordx4 per line -> L2 write-combines.
    f32x4* __restrict__ o4 = reinterpret_cast<f32x4*>(out) + (size_t)t * CH;
    #pragma unroll
    for (int k = 0; k < CH; ++k) {
        const int j = 4 * k;
        f32x4 v;
        v.x = (j + 0 == i1) ? w1 : ((j + 0 == i2) ? w2 : 0.0f);
        v.y = (j + 1 == i1) ? w1 : ((j + 1 == i2) ? w2 : 0.0f);
        v.z = (j + 2 == i1) ? w1 : ((j + 2 == i2) ? w2 : 0.0f);
        v.w = (j + 3 == i1) ? w1 : ((j + 3 == i2) ? w2 : 0.0f);
        o4[k] = v;
    }
}

extern "C" void kernel_launch(void* const* d_in, const int* in_sizes, int n_in,
                              void* d_out, int out_size, void* d_ws, size_t ws_size,
                              hipStream_t stream) {
    const float* x = (const float*)d_in[0];
    const float* W = (const float*)d_in[1];
    float* out = (float*)d_out;
    int ntok = in_sizes[0] / DIM;                    // 262144

    int blocks = (ntok + 63) / 64;                   // 4096 one-wave blocks
    moe_router_kernel<<<blocks, 64, 0, stream>>>(x, W, out, ntok);
}